// Round 2
// baseline (163.164 us; speedup 1.0000x reference)
//
#include <hip/hip_runtime.h>
#include <math.h>

#define NQ 131072
#define MN 8192
#define NINT 1024          // internal nodes: 8*i+1 < 8192 -> i <= 1023
#define DEPTHT 16
#define EPSD 1e-6f
#define BIGD 1e9f

// ---------------------------------------------------------------------------
// Kernel 0: transpose W2 [k][j] -> W2T [j][k], rows PADDED to 128 floats so
// every row is exactly 8 aligned 64B K$ lines (aligned dwordx16 bursts).
// ---------------------------------------------------------------------------
__global__ __launch_bounds__(256) void transpose_w2(
    const float* __restrict__ W2, float* __restrict__ W2T)
{
    const int i = blockIdx.x * 256 + threadIdx.x;
    if (i < 100 * 100) {
        const int k = i / 100, j = i - k * 100;
        W2T[j * 128 + k] = W2[i];
    }
}

// ---------------------------------------------------------------------------
// Kernel 1: MLP 2 -> 100 -> 100 -> 30 -> 2, one row per thread.
// Per-thread dag VERBATIM (bit-identical association; R5 proved any
// reassociation fails; R10 convoy barriers REGRESSED 69->77us -> reverted to
// 64-thread single-wave blocks, grid 2176).
// R11 change: HYBRID WEIGHT TRANSPORT.
// Theory: stall is dependent-burst serialization on the scalar path.
// SGPR file (112) is full: a w2 row alone wants 100 SGPRs, so the compiler
// cannot prefetch row j+1 while consuming row j, and the w3 burst (30
// floats) is a SECOND dependent scalar burst per iter. Measured 790
// cyc/iter/wave vs 260 cyc VALU issue -> ~530 cyc exposed lgkm latency.
// Fix: w3 + b2 move to LDS (staged once/block; uniform-address ds_read is
// a conflict-free broadcast). Deletes the second scalar burst, frees ~40
// SGPRs for w2 row prefetch, and ds_read latency overlaps s_load latency.
// Same bits, same FMA order: zero numeric risk.
// Expected: mlp 69 -> 45-58us, VALUBusy 35 -> 45-55%.
// ---------------------------------------------------------------------------
__global__ __launch_bounds__(64, 2) void mlp_kernel(
    const float* __restrict__ x, const float* __restrict__ nd,
    const float* __restrict__ W1, const float* __restrict__ b1,
    const float* __restrict__ W2T, const float* __restrict__ b2,
    const float* __restrict__ W3, const float* __restrict__ b3,
    const float* __restrict__ W4, const float* __restrict__ b4,
    float* __restrict__ outv)
{
    __shared__ float sw3[100 * 32];   // rows padded to 32 floats (16B-aligned)
    __shared__ float sb2[128];

    // ---- stage w3 + b2 to LDS (once per 1-wave block) ----
    {
        const int tid = threadIdx.x;
        for (int t = tid; t < 3200; t += 64) {
            const int j = t >> 5, k = t & 31;
            sw3[t] = (k < 30) ? W3[j * 30 + k] : 0.0f;
        }
        for (int t = tid; t < 100; t += 64) sb2[t] = b2[t];
    }
    __syncthreads();

    const int r = blockIdx.x * 64 + threadIdx.x;    // 2176*64 = 139264 exact
    const float2 xi = (r < NQ) ? ((const float2*)x)[r]
                               : ((const float2*)nd)[r - NQ];

    // ---- layer 1: h1[100] in registers (constant indices only) ----
    float h1[100];
#pragma unroll
    for (int k = 0; k < 100; ++k)
        h1[k] = fmaxf(fmaf(xi.x, W1[k], fmaf(xi.y, W1[100 + k], b1[k])), 0.0f);

    // ---- layers 2+3 fused: h2j = relu(h1 . W2T[j] + b2[j]) folded into h3
    //      immediately (h2 never materialized). w2: s_load; w3/b2: LDS ----
    float h3[30];
#pragma unroll
    for (int jj = 0; jj < 30; ++jj) h3[jj] = b3[jj];

    const float* w2 = W2T;              // padded stride 128 (8 K$ lines/row)
    const float* w3l = sw3;             // LDS, padded stride 32
    for (int j = 0; j < 100; ++j) {
        float a0 = 0.0f, a1 = 0.0f;     // 2 chains: hide FMA latency
#pragma unroll
        for (int k = 0; k < 100; k += 2) {
            a0 = fmaf(h1[k],     w2[k],     a0);    // w2[k]: s_load scalar
            a1 = fmaf(h1[k + 1], w2[k + 1], a1);
        }
        const float h2j = fmaxf(a0 + a1 + sb2[j], 0.0f);
#pragma unroll
        for (int jj = 0; jj < 30; ++jj)
            h3[jj] = fmaf(h2j, w3l[jj], h3[jj]);    // w3: LDS broadcast
        w2 += 128;
        w3l += 32;
    }

    // ---- layer 4: 30 -> 2 ----
    float o0 = b4[0], o1 = b4[1];
#pragma unroll
    for (int k = 0; k < 30; ++k) {
        const float h = fmaxf(h3[k], 0.0f);
        o0 = fmaf(h, W4[2 * k],     o0);
        o1 = fmaf(h, W4[2 * k + 1], o1);
    }
    ((float2*)outv)[r] = make_float2(o0, o1);
}

// ---------------------------------------------------------------------------
// Kernel 2: per-internal-node stop-branch class mixture (query-independent).
// Verbatim rounds 3/6/7/8/9 (passed).
// ---------------------------------------------------------------------------
__global__ __launch_bounds__(256) void prob2_kernel(
    const float2* __restrict__ emb, const float2* __restrict__ cls,
    float2* __restrict__ p2)
{
    const int i = blockIdx.x * 256 + threadIdx.x;   // 0..1023
    const float2 ei = emb[i];
    const int base = 8 * i + 1;

    float d2[8];
    float m2 = BIGD;
#pragma unroll
    for (int j = 0; j < 8; ++j) {
        const int c = base + j;
        const bool v = c < MN;
        const float2 ec = emb[v ? c : 0];
        const float dx = ei.x - ec.x + EPSD;
        const float dy = ei.y - ec.y + EPSD;
        d2[j] = v ? sqrtf(dx * dx + dy * dy) : BIGD;
        m2 = fminf(m2, d2[j]);
    }
    float s2 = 0.0f, mix0 = 0.0f, mix1 = 0.0f;
#pragma unroll
    for (int j = 0; j < 8; ++j) {
        const float w = expf(m2 - d2[j]);   // exactly 0 for pads
        s2 += w;
        const int c = base + j;
        if (c < MN) {
            const float2 cv = cls[c];
            mix0 = fmaf(w, cv.x, mix0);
            mix1 = fmaf(w, cv.y, mix1);
        }
    }
    mix0 /= s2;
    mix1 /= s2;
    p2[i] = make_float2(logf(fmaxf(mix0, 1e-30f)),
                        logf(fmaxf(mix1, 1e-30f)));
}

// ---------------------------------------------------------------------------
// Kernel 3: per-query traversal. Verbatim rounds 6/7/8/9 (passed): emb + p2
// staged to LDS; d0 carried across steps (child dist at t == d0 at t+1).
// ---------------------------------------------------------------------------
__global__ __launch_bounds__(256) void traverse_kernel(
    const float* __restrict__ qx, const float2* __restrict__ emb,
    const float2* __restrict__ p2g, float* __restrict__ out)
{
    __shared__ float2 semb[MN];     // 64 KB
    __shared__ float2 sp2[NINT];    // 8 KB
    {
        const float4* ge = (const float4*)emb;
        float4* se = (float4*)semb;
#pragma unroll
        for (int t = 0; t < 16; ++t)
            se[threadIdx.x + 256 * t] = ge[threadIdx.x + 256 * t];
        const float4* gp = (const float4*)p2g;
        float4* sp = (float4*)sp2;
#pragma unroll
        for (int t = 0; t < 2; ++t)
            sp[threadIdx.x + 256 * t] = gp[threadIdx.x + 256 * t];
    }
    __syncthreads();

    const int qi = blockIdx.x * 256 + threadIdx.x;  // grid = NQ/256
    const float2 qv = ((const float2*)qx)[qi];

    int cur = 0;
    float d0;
    {
        const float2 e0 = semb[0];
        const float dx = e0.x - qv.x + EPSD;
        const float dy = e0.y - qv.y + EPSD;
        d0 = sqrtf(dx * dx + dy * dy);
    }
    float prob = 0.0f, out0 = 0.0f, out1 = 0.0f;
    bool done = false;

    for (int t = 0; t < DEPTHT; ++t) {
        if (__all(done)) break;
        if (!done) {
            const int base = 8 * cur + 1;

            float dc[8];
#pragma unroll
            for (int j = 0; j < 8; ++j) {
                const int c = base + j;
                const bool v = c < MN;
                const float2 e = semb[v ? c : 0];
                const float dx = e.x - qv.x + EPSD;
                const float dy = e.y - qv.y + EPSD;
                dc[j] = v ? sqrtf(dx * dx + dy * dy) : BIGD;
            }

            // argmax(log_softmax(-d)) == first argmin(d)
            float dmin = d0;
            int amax = 0;
#pragma unroll
            for (int j = 0; j < 8; ++j)
                if (dc[j] < dmin) { dmin = dc[j]; amax = j + 1; }

            float s = expf(dmin - d0);
#pragma unroll
            for (int j = 0; j < 8; ++j) s += expf(dmin - dc[j]);
            const float max_prob = -logf(s);
            // quirk: t==0 adds max_prob twice
            const float prob_new = prob + max_prob + ((t == 0) ? max_prob : 0.0f);

            if (amax == 0) {
                if (base < MN) {                  // internal node
                    const float2 pp = sp2[cur];
                    out0 = prob_new + pp.x;
                    out1 = prob_new + pp.y;
                } else {                          // leaf
                    out0 = prob_new;
                    out1 = prob_new;
                }
                done = true;
            } else {
                cur  = base + amax - 1;
                d0   = dmin;                      // child dist == next d0
                prob = prob_new;
            }
        }
    }

    ((float2*)out)[qi] = make_float2(out0, out1);
}

// ---------------------------------------------------------------------------
extern "C" void kernel_launch(void* const* d_in, const int* in_sizes, int n_in,
                              void* d_out, int out_size, void* d_ws, size_t ws_size,
                              hipStream_t stream)
{
    const float* x   = (const float*)d_in[0];
    const float* nd  = (const float*)d_in[1];
    const float* cls = (const float*)d_in[2];
    // d_in[3] (children) unused: complete 8-ary tree, child = 8i+1+j if <8192
    const float* W1 = (const float*)d_in[4];
    const float* b1 = (const float*)d_in[5];
    const float* W2 = (const float*)d_in[6];
    const float* b2 = (const float*)d_in[7];
    const float* W3 = (const float*)d_in[8];
    const float* b3 = (const float*)d_in[9];
    const float* W4 = (const float*)d_in[10];
    const float* b4 = (const float*)d_in[11];

    float* ws   = (float*)d_ws;
    float* qx   = ws;                        // [NQ][2]
    float* embf = ws + 2 * NQ;               // [MN][2]
    float* p2f  = ws + 2 * (NQ + MN);        // [NINT][2]
    float* w2t  = p2f + 2 * NINT;            // [100][128] padded rows

    transpose_w2<<<40, 256, 0, stream>>>(W2, w2t);

    mlp_kernel<<<(NQ + MN) / 64, 64, 0, stream>>>(
        x, nd, W1, b1, w2t, b2, W3, b3, W4, b4, qx);

    prob2_kernel<<<NINT / 256, 256, 0, stream>>>(
        (const float2*)embf, (const float2*)cls, (float2*)p2f);

    traverse_kernel<<<NQ / 256, 256, 0, stream>>>(
        qx, (const float2*)embf, (const float2*)p2f, (float*)d_out);
}

// Round 3
// 156.007 us; speedup vs baseline: 1.0459x; 1.0459x over previous
//
#include <hip/hip_runtime.h>
#include <math.h>

#define NQ 131072
#define MN 8192
#define NINT 1024          // internal nodes: 8*i+1 < 8192 -> i <= 1023
#define DEPTHT 16
#define EPSD 1e-6f
#define BIGD 1e9f

// ---------------------------------------------------------------------------
// Kernel 0: transpose W2 [k][j] -> W2T [j][k] (contiguous rows for s_load).
// Verbatim R0 (stride 100; the 128-pad variants R1/R2 were never a win).
// ---------------------------------------------------------------------------
__global__ __launch_bounds__(256) void transpose_w2(
    const float* __restrict__ W2, float* __restrict__ W2T)
{
    const int i = blockIdx.x * 256 + threadIdx.x;
    if (i < 100 * 100) {
        const int k = i / 100, j = i - k * 100;
        W2T[j * 100 + k] = W2[i];
    }
}

// ---------------------------------------------------------------------------
// Kernel 1: MLP 2 -> 100 -> 100 -> 30 -> 2, one row per thread.
// EXACT R0 69.2us version (64-thread single-wave blocks, all-scalar weight
// stream). Journal of failed variants — do not retry:
//   R10 convoy (256-thr + barriers every 10 j): 77.9us. Phase-locking
//     removed wave-drift latency hiding; K$ lines are NOT usefully shared.
//   R11 w3->LDS hybrid: 80.0us. SMEM and DS share lgkmcnt and SMEM returns
//     out-of-order -> mixing ds_read into the s_load loop forces full-drain
//     waits, killing the compiler's w2 prefetch. Never mix DS with the
//     scalar weight stream in this loop.
// Weight transport scoreboard (prior session): s_load 71 < LDS 98 < VMEM 290.
// Do not touch the dag: traversal is chaotic; FP association of every chain
// is part of the correctness contract (R5 failed on a reassociation).
// ---------------------------------------------------------------------------
__global__ __launch_bounds__(64, 2) void mlp_kernel(
    const float* __restrict__ x, const float* __restrict__ nd,
    const float* __restrict__ W1, const float* __restrict__ b1,
    const float* __restrict__ W2T, const float* __restrict__ b2,
    const float* __restrict__ W3, const float* __restrict__ b3,
    const float* __restrict__ W4, const float* __restrict__ b4,
    float* __restrict__ outv)
{
    const int r = blockIdx.x * 64 + threadIdx.x;    // 2176*64 = 139264 exact
    const float2 xi = (r < NQ) ? ((const float2*)x)[r]
                               : ((const float2*)nd)[r - NQ];

    // ---- layer 1: h1[100] in VGPRs (constant indices only) ----
    float h1[100];
#pragma unroll
    for (int k = 0; k < 100; ++k)
        h1[k] = fmaxf(fmaf(xi.x, W1[k], fmaf(xi.y, W1[100 + k], b1[k])), 0.0f);

    // ---- layers 2+3 fused: h2j = relu(h1 . W2T[j] + b2[j]) folded into h3
    //      immediately (h2 never materialized); weights all s_load uniform ----
    float h3[30];
#pragma unroll
    for (int jj = 0; jj < 30; ++jj) h3[jj] = b3[jj];

    const float* w2 = W2T;
    const float* w3 = W3;
    for (int j = 0; j < 100; ++j) {
        float a0 = 0.0f, a1 = 0.0f;                 // 2 chains: hide FMA latency
#pragma unroll
        for (int k = 0; k < 100; k += 2) {
            a0 = fmaf(h1[k],     w2[k],     a0);    // w2[k]: s_load scalar
            a1 = fmaf(h1[k + 1], w2[k + 1], a1);
        }
        const float h2j = fmaxf(a0 + a1 + b2[j], 0.0f);
#pragma unroll
        for (int jj = 0; jj < 30; ++jj)
            h3[jj] = fmaf(h2j, w3[jj], h3[jj]);     // w3[jj]: s_load scalar
        w2 += 100;
        w3 += 30;
    }

    // ---- layer 4: 30 -> 2 ----
    float o0 = b4[0], o1 = b4[1];
#pragma unroll
    for (int k = 0; k < 30; ++k) {
        const float h = fmaxf(h3[k], 0.0f);
        o0 = fmaf(h, W4[2 * k],     o0);
        o1 = fmaf(h, W4[2 * k + 1], o1);
    }
    ((float2*)outv)[r] = make_float2(o0, o1);
}

// ---------------------------------------------------------------------------
// Kernel 2: per-internal-node stop-branch class mixture (query-independent).
// Verbatim rounds 3/6/7/8/9 (passed).
// ---------------------------------------------------------------------------
__global__ __launch_bounds__(256) void prob2_kernel(
    const float2* __restrict__ emb, const float2* __restrict__ cls,
    float2* __restrict__ p2)
{
    const int i = blockIdx.x * 256 + threadIdx.x;   // 0..1023
    const float2 ei = emb[i];
    const int base = 8 * i + 1;

    float d2[8];
    float m2 = BIGD;
#pragma unroll
    for (int j = 0; j < 8; ++j) {
        const int c = base + j;
        const bool v = c < MN;
        const float2 ec = emb[v ? c : 0];
        const float dx = ei.x - ec.x + EPSD;
        const float dy = ei.y - ec.y + EPSD;
        d2[j] = v ? sqrtf(dx * dx + dy * dy) : BIGD;
        m2 = fminf(m2, d2[j]);
    }
    float s2 = 0.0f, mix0 = 0.0f, mix1 = 0.0f;
#pragma unroll
    for (int j = 0; j < 8; ++j) {
        const float w = expf(m2 - d2[j]);   // exactly 0 for pads
        s2 += w;
        const int c = base + j;
        if (c < MN) {
            const float2 cv = cls[c];
            mix0 = fmaf(w, cv.x, mix0);
            mix1 = fmaf(w, cv.y, mix1);
        }
    }
    mix0 /= s2;
    mix1 /= s2;
    p2[i] = make_float2(logf(fmaxf(mix0, 1e-30f)),
                        logf(fmaxf(mix1, 1e-30f)));
}

// ---------------------------------------------------------------------------
// Kernel 3: per-query traversal. R12 change: BANK-DECORRELATED LDS LAYOUT.
// Defect found by arithmetic: children of cur are float2 semb[8cur+1..8cur+8];
// dword bank of child j = (16cur+2+2j)%32 — only cur&1 matters, so each of
// the 8 ds_read_b64/level put ~32 lanes on one bank-pair (~32-way conflict,
// ~11x serialization, every level, every wave; 8 waves share one LDS unit).
// Fix: node c stored at float offset 2c + (c>>3) (1 pad dword per 8 nodes).
// Child-j offset = 17*cur + 2 + 2j (+1 if j==7); 17 coprime 32 -> random
// per-lane cur spreads all 32 banks (~2-4-way residual ~ free, m136).
// Same values, same FMA/sqrt/exp order -> bit-identical output.
// d0 carried across steps (child dist at t == d0 at t+1), verbatim.
// ---------------------------------------------------------------------------
#define SEMB_F (2 * MN + MN / 8)    // 17408 floats = 68 KB

__global__ __launch_bounds__(256) void traverse_kernel(
    const float* __restrict__ qx, const float2* __restrict__ emb,
    const float2* __restrict__ p2g, float* __restrict__ out)
{
    __shared__ float sembf[SEMB_F];  // 68 KB, padded layout
    __shared__ float2 sp2[NINT];     // 8 KB
    {
        for (int c = threadIdx.x; c < MN; c += 256) {   // coalesced 8B/lane
            const float2 e = emb[c];
            const int off = 2 * c + (c >> 3);
            sembf[off]     = e.x;
            sembf[off + 1] = e.y;
        }
        const float4* gp = (const float4*)p2g;
        float4* sp = (float4*)sp2;
#pragma unroll
        for (int t = 0; t < 2; ++t)
            sp[threadIdx.x + 256 * t] = gp[threadIdx.x + 256 * t];
    }
    __syncthreads();

    const int qi = blockIdx.x * 256 + threadIdx.x;  // grid = NQ/256
    const float2 qv = ((const float2*)qx)[qi];

    int cur = 0;
    float d0;
    {
        const float ex = sembf[0], ey = sembf[1];   // node 0 at offset 0
        const float dx = ex - qv.x + EPSD;
        const float dy = ey - qv.y + EPSD;
        d0 = sqrtf(dx * dx + dy * dy);
    }
    float prob = 0.0f, out0 = 0.0f, out1 = 0.0f;
    bool done = false;

    for (int t = 0; t < DEPTHT; ++t) {
        if (__all(done)) break;
        if (!done) {
            const int base = 8 * cur + 1;
            const int boff = 17 * cur + 2;          // float offset of child 0

            float dc[8];
#pragma unroll
            for (int j = 0; j < 8; ++j) {
                const int c = base + j;
                const bool v = c < MN;
                const int off = v ? (boff + 2 * j + (j == 7 ? 1 : 0)) : 0;
                const float ex = sembf[off];
                const float ey = sembf[off + 1];
                const float dx = ex - qv.x + EPSD;
                const float dy = ey - qv.y + EPSD;
                dc[j] = v ? sqrtf(dx * dx + dy * dy) : BIGD;
            }

            // argmax(log_softmax(-d)) == first argmin(d)
            float dmin = d0;
            int amax = 0;
#pragma unroll
            for (int j = 0; j < 8; ++j)
                if (dc[j] < dmin) { dmin = dc[j]; amax = j + 1; }

            float s = expf(dmin - d0);
#pragma unroll
            for (int j = 0; j < 8; ++j) s += expf(dmin - dc[j]);
            const float max_prob = -logf(s);
            // quirk: t==0 adds max_prob twice
            const float prob_new = prob + max_prob + ((t == 0) ? max_prob : 0.0f);

            if (amax == 0) {
                if (base < MN) {                  // internal node
                    const float2 pp = sp2[cur];
                    out0 = prob_new + pp.x;
                    out1 = prob_new + pp.y;
                } else {                          // leaf
                    out0 = prob_new;
                    out1 = prob_new;
                }
                done = true;
            } else {
                cur  = base + amax - 1;
                d0   = dmin;                      // child dist == next d0
                prob = prob_new;
            }
        }
    }

    ((float2*)out)[qi] = make_float2(out0, out1);
}

// ---------------------------------------------------------------------------
extern "C" void kernel_launch(void* const* d_in, const int* in_sizes, int n_in,
                              void* d_out, int out_size, void* d_ws, size_t ws_size,
                              hipStream_t stream)
{
    const float* x   = (const float*)d_in[0];
    const float* nd  = (const float*)d_in[1];
    const float* cls = (const float*)d_in[2];
    // d_in[3] (children) unused: complete 8-ary tree, child = 8i+1+j if <8192
    const float* W1 = (const float*)d_in[4];
    const float* b1 = (const float*)d_in[5];
    const float* W2 = (const float*)d_in[6];
    const float* b2 = (const float*)d_in[7];
    const float* W3 = (const float*)d_in[8];
    const float* b3 = (const float*)d_in[9];
    const float* W4 = (const float*)d_in[10];
    const float* b4 = (const float*)d_in[11];

    float* ws   = (float*)d_ws;
    float* qx   = ws;                        // [NQ][2]
    float* embf = ws + 2 * NQ;               // [MN][2]
    float* p2f  = ws + 2 * (NQ + MN);        // [NINT][2]
    float* w2t  = p2f + 2 * NINT;            // [100][100]

    transpose_w2<<<40, 256, 0, stream>>>(W2, w2t);

    mlp_kernel<<<(NQ + MN) / 64, 64, 0, stream>>>(
        x, nd, W1, b1, w2t, b2, W3, b3, W4, b4, qx);

    prob2_kernel<<<NINT / 256, 256, 0, stream>>>(
        (const float2*)embf, (const float2*)cls, (float2*)p2f);

    traverse_kernel<<<NQ / 256, 256, 0, stream>>>(
        qx, (const float2*)embf, (const float2*)p2f, (float*)d_out);
}